// Round 12
// baseline (418.295 us; speedup 1.0000x reference)
//
#include <hip/hip_runtime.h>
#include <stdint.h>

#define T_LEN 1024
#define NSTATE 32
#define RING 32

typedef int v2i __attribute__((ext_vector_type(2)));

__device__ __forceinline__ float max3f(float a, float b, float c) {
    return fmaxf(fmaxf(a, b), c);   // v_max3_f32
}
__device__ __forceinline__ int min3i(int a, int b, int c) {
    return min(min(a, b), c);       // v_min3_i32
}

// DPP row-rotate by n within each 16-lane row (pure VALU, no LDS pipe)
#define ROR(x, n) __builtin_amdgcn_mov_dpp((x), 0x120 + (n), 0xF, 0xF, false)

__device__ __forceinline__ void gather16(int x, int g[16]) {
    g[0]  = x;
    g[1]  = ROR(g[0], 1);
    g[2]  = ROR(g[0], 2);
    g[3]  = ROR(g[1], 2);
    g[4]  = ROR(g[0], 4);
    g[5]  = ROR(g[1], 4);
    g[6]  = ROR(g[2], 4);
    g[7]  = ROR(g[3], 4);
    g[8]  = ROR(g[0], 8);
    g[9]  = ROR(g[1], 8);
    g[10] = ROR(g[2], 8);
    g[11] = ROR(g[3], 8);
    g[12] = ROR(g[4], 8);
    g[13] = ROR(g[5], 8);
    g[14] = ROR(g[6], 8);
    g[15] = ROR(g[7], 8);
}

// Exchange with lane^16 (row swap). Convention-proof partner extraction.
__device__ __forceinline__ int xrow16_partner(int own) {
    int a = own, b = own;
#if __has_builtin(__builtin_amdgcn_permlane16_swap)
    v2i r = __builtin_amdgcn_permlane16_swap(a, b, false, false);
    a = r[0]; b = r[1];
#else
    asm volatile("v_permlane16_swap_b32 %0, %1" : "+v"(a), "+v"(b));
#endif
    return (a == own) ? b : a;
}

// wave 0 = MAIN: serial value chain only (DPP broadcast, no argmax).
// wave 1 = HELPER: recomputes gm (bit-exact) from the LDS ring, does the
// argmax cascade + bp writes, batched 8 steps per flag check.
__launch_bounds__(128)
__global__ void viterbi_kernel(const float* __restrict__ logits,
                               const float* __restrict__ trans,
                               const int* __restrict__ seqlen,
                               int* __restrict__ out)
{
    const int tid  = threadIdx.x;   // 0..127
    const int wid  = tid >> 6;      // 0 = main, 1 = helper
    const int lane = tid & 63;
    const int half = lane >> 5;
    const int j    = lane & 31;
    const int h16  = half * 16;
    const int myidx = (lane < 32) ? j : (j ^ 16);   // main-wave state layout
    const bool upper = lane >= 32;

    __shared__ uint8_t bp[T_LEN * NSTATE];                 // 32 KB backptrs
    __shared__ __align__(16) char ovl[RING * NSTATE * 4];  // ring / pred overlay
    __shared__ uint8_t Farr[NSTATE * NSTATE];
    __shared__ uint8_t earr[NSTATE];
    __shared__ volatile int flag[RING];                    // slot -> step stored
    __shared__ volatile int hp;                            // helper progress

    float (*st_ring)[NSTATE] = (float (*)[NSTATE])ovl;
    int* pred = (int*)ovl;                                 // epilogue only

    if (tid < RING) flag[tid] = -1;
    if (tid == 0) hp = 0;

    int L = seqlen[blockIdx.x];
    L = min(max(L, 0), T_LEN);

    const float* lg = logits + (size_t)blockIdx.x * T_LEN * NSTATE;

    __syncthreads();     // flags/hp initialized

    int ft = 0;

    if (wid == 0) {
        // ================= MAIN =================
        // probe pidx through the same DPP network (direction-proof)
        int pidx[16];
        gather16(myidx, pidx);
        float tr_rot[16];
#pragma unroll
        for (int k = 0; k < 16; ++k)
            tr_rot[k] = trans[pidx[k] * NSTATE + j];

        float ns = lg[myidx];            // lane holds state[myidx]

        st_ring[0][myidx] = ns;          // publish S_0 (2 dup writers/addr)
        __asm__ __volatile__("" ::: "memory");
        flag[0] = 0;

        auto mstep = [&](int t, float lgt) {
            int gb[16];
            gather16(__float_as_int(ns), gb);     // 15 v_mov_dpp

            float v[16];
#pragma unroll
            for (int k = 0; k < 16; ++k)
                v[k] = __int_as_float(gb[k]) + tr_rot[k];

            float a0 = max3f(v[0],  v[1],  v[2]);
            float a1 = max3f(v[3],  v[4],  v[5]);
            float a2 = max3f(v[6],  v[7],  v[8]);
            float a3 = max3f(v[9],  v[10], v[11]);
            float a4 = max3f(v[12], v[13], v[14]);
            float b0 = max3f(a0, a1, a2);
            float b1 = max3f(a3, a4, v[15]);
            float hm = fmaxf(b0, b1);

            v2i sw = __builtin_amdgcn_permlane32_swap(__float_as_int(hm),
                                                      __float_as_int(hm), false, false);
            float gm = fmaxf(hm, fmaxf(__int_as_float(sw[0]), __int_as_float(sw[1])));

            ns = gm + lgt;               // reference add order

            // throttle: distance 12 > hp granularity 8; checked every 4 steps
            if ((t & 3) == 0) {
                while (t - hp > 12) __builtin_amdgcn_s_sleep(2);
            }

            const int slot = t & (RING - 1);
            st_ring[slot][j] = ns;                // all lanes: addr j, dup value
            __asm__ __volatile__("" ::: "memory");
            flag[slot] = t;                       // data-then-flag (pipe FIFO)

            // relayout so lane holds s[myidx] for the next gather
            int part = xrow16_partner(__float_as_int(ns));
            if (upper) ns = __int_as_float(part);
        };

        if (L >= 2) {
            float pre[8];
#pragma unroll
            for (int d = 0; d < 8; ++d)
                pre[d] = lg[min(1 + d, T_LEN - 1) * NSTATE + j];
            int t = 1;
            for (; t + 8 <= L; t += 8) {
#pragma unroll
                for (int u = 0; u < 8; ++u) {
                    mstep(t + u, pre[u]);
                    pre[u] = lg[min(t + 8 + u, T_LEN - 1) * NSTATE + j];
                }
            }
            for (int k2 = 0; t < L; ++t, ++k2) mstep(t, pre[k2]);
        }

        // last_tag: every state value appears exactly twice (at myidx)
        float m2 = ns;
#pragma unroll
        for (int d = 1; d < 64; d <<= 1) m2 = fmaxf(m2, __shfl_xor(m2, d));
        int ii = (ns == m2) ? myidx : 64;
#pragma unroll
        for (int d = 1; d < 64; d <<= 1) ii = min(ii, __shfl_xor(ii, d));
        ft = ii;
    } else {
        // ================= HELPER =================
        float tr[16];
#pragma unroll
        for (int k = 0; k < 16; ++k)
            tr[k] = trans[(h16 + k) * NSTATE + j];

        auto hstep = [&](int t) {
            const float4* sv = (const float4*)(st_ring[(t - 1) & (RING - 1)]) + half * 4;
            float4 q0 = sv[0], q1 = sv[1], q2 = sv[2], q3 = sv[3];

            float v[16];
            v[0]=q0.x+tr[0];  v[1]=q0.y+tr[1];  v[2]=q0.z+tr[2];  v[3]=q0.w+tr[3];
            v[4]=q1.x+tr[4];  v[5]=q1.y+tr[5];  v[6]=q1.z+tr[6];  v[7]=q1.w+tr[7];
            v[8]=q2.x+tr[8];  v[9]=q2.y+tr[9];  v[10]=q2.z+tr[10];v[11]=q2.w+tr[11];
            v[12]=q3.x+tr[12];v[13]=q3.y+tr[13];v[14]=q3.z+tr[14];v[15]=q3.w+tr[15];

            // gm recompute — fmax is assoc/comm: bit-identical to main's gm
            float a0 = max3f(v[0],  v[1],  v[2]);
            float a1 = max3f(v[3],  v[4],  v[5]);
            float a2 = max3f(v[6],  v[7],  v[8]);
            float a3 = max3f(v[9],  v[10], v[11]);
            float a4 = max3f(v[12], v[13], v[14]);
            float b0 = max3f(a0, a1, a2);
            float b1 = max3f(a3, a4, v[15]);
            float hm = fmaxf(b0, b1);
            v2i sw = __builtin_amdgcn_permlane32_swap(__float_as_int(hm),
                                                      __float_as_int(hm), false, false);
            float gm = fmaxf(hm, fmaxf(__int_as_float(sw[0]), __int_as_float(sw[1])));

            // exact first-occurrence argmax
            int ix[16];
#pragma unroll
            for (int k = 0; k < 16; ++k)
                ix[k] = (v[k] == gm) ? (h16 + k) : 64;
            int c0 = min3i(ix[0],  ix[1],  ix[2]);
            int c1 = min3i(ix[3],  ix[4],  ix[5]);
            int c2 = min3i(ix[6],  ix[8],  ix[7]);
            int c3 = min3i(ix[9],  ix[10], ix[11]);
            int c4 = min3i(ix[12], ix[13], ix[14]);
            int d0 = min3i(c0, c1, c2);
            int d1 = min3i(c3, c4, ix[15]);
            int ih = min(d0, d1);
            v2i swi = __builtin_amdgcn_permlane32_swap(ih, ih, false, false);
            int idx = min3i(ih, swi[0], swi[1]);

            bp[t * NSTATE + j] = (uint8_t)idx;    // dup same-value write
        };

        if (L >= 2) {
            int t = 1;
            // batches of 8: one flag check covers S_{t-1}..S_{t+6}
            for (; t + 7 <= L - 1; t += 8) {
                const int need = t + 6;
                while (flag[need & (RING - 1)] < need) __builtin_amdgcn_s_sleep(1);
                __asm__ __volatile__("" ::: "memory");
#pragma unroll
                for (int u = 0; u < 8; ++u) hstep(t + u);
                hp = t + 7;                       // progress for main throttle
            }
            for (; t <= L - 1; ++t) {             // tail: per-step check
                const int need = t - 1;
                while (flag[need & (RING - 1)] < need) __builtin_amdgcn_s_sleep(1);
                __asm__ __volatile__("" ::: "memory");
                hstep(t);
            }
            hp = 1 << 20;                         // full release
        }
    }

    __syncthreads();   // bp complete; st_ring dead (pred overlays it)

    // ---- phase 1: chunk functions, all 32 start states (wave 0) ----
    if (wid == 0) {
        const int c = lane & 31;
        const int j0base = (lane >> 5) * 16;
        int tags[16];
#pragma unroll
        for (int k = 0; k < 16; ++k) tags[k] = j0base + k;
        const int thi = c * 32 + 31;
        for (int s = 0; s < 32; ++s) {
            int t = thi - s;
            bool valid = (t >= 1) && (t <= L - 1);
            int tc = min(max(t, 1), max(L - 1, 1));
            int base = tc * NSTATE;
#pragma unroll
            for (int k = 0; k < 16; ++k) {
                int nt = bp[base + tags[k]];
                tags[k] = valid ? nt : tags[k];
            }
        }
#pragma unroll
        for (int k = 0; k < 16; ++k)
            Farr[c * 32 + j0base + k] = (uint8_t)tags[k];
    }
    __syncthreads();

    // ---- phase 2: compose chunk entries ----
    if (tid == 0) {
        int e = ft;
        for (int c2 = 31; c2 >= 0; --c2) {
            earr[c2] = (uint8_t)e;
            e = Farr[c2 * 32 + e];
        }
    }
    __syncthreads();

    // ---- phase 3: re-walk chunks, emit pred (predication handles L<2) ----
    if (wid == 0 && lane < 32) {
        int tag = earr[lane];
        const int thi3 = lane * 32 + 31;
        for (int s = 0; s < 32; ++s) {
            int t = thi3 - s;
            pred[t] = (t < L) ? tag : 0;
            bool valid = (t >= 1) && (t <= L - 1);
            int tc = min(max(t, 1), max(L - 1, 1));
            int nt = bp[tc * NSTATE + tag];
            tag = valid ? nt : tag;
        }
    }
    __syncthreads();

    // ---------------- coalesced store (wave 0) ----------------
    if (wid == 0) {
        int4* out4 = reinterpret_cast<int4*>(out + (size_t)blockIdx.x * T_LEN);
        const int4* p4 = reinterpret_cast<const int4*>(pred);
#pragma unroll
        for (int r = 0; r < 4; ++r)
            out4[r * 64 + lane] = p4[r * 64 + lane];
    }
}

extern "C" void kernel_launch(void* const* d_in, const int* in_sizes, int n_in,
                              void* d_out, int out_size, void* d_ws, size_t ws_size,
                              hipStream_t stream) {
    const float* logits = (const float*)d_in[0];
    const float* trans  = (const float*)d_in[1];
    const int*   slen   = (const int*)d_in[2];
    int*         out    = (int*)d_out;
    const int B = in_sizes[2];   // 1024

    viterbi_kernel<<<dim3(B), dim3(128), 0, stream>>>(logits, trans, slen, out);
}

// Round 13
// 301.153 us; speedup vs baseline: 1.3890x; 1.3890x over previous
//
#include <hip/hip_runtime.h>
#include <stdint.h>

#define T_LEN 1024
#define NSTATE 32
#define RING 32

typedef int v2i __attribute__((ext_vector_type(2)));

__device__ __forceinline__ float max3f(float a, float b, float c) {
    return fmaxf(fmaxf(a, b), c);   // v_max3_f32
}
__device__ __forceinline__ int min3i(int a, int b, int c) {
    return min(min(a, b), c);       // v_min3_i32
}

// wave 0 = MAIN: minimal serial value chain + ring publish (no argmax).
// waves 1,2 = HELPERS: split timesteps by parity; each recomputes gm
// (bit-exact: fmax of the same 32 floats) and does argmax + bp write.
// Sync: single monotonic LDS counter mp (lane-0 writes), per-batch polls.
__launch_bounds__(192)
__global__ void viterbi_kernel(const float* __restrict__ logits,
                               const float* __restrict__ trans,
                               const int* __restrict__ seqlen,
                               int* __restrict__ out)
{
    const int tid  = threadIdx.x;   // 0..191
    const int wid  = tid >> 6;      // 0 main, 1 odd-t helper, 2 even-t helper
    const int lane = tid & 63;
    const int half = lane >> 5;
    const int j    = lane & 31;
    const int h16  = half * 16;

    __shared__ uint8_t bp[T_LEN * NSTATE];               // 32 KB backptrs
    __shared__ __align__(16) float ring[RING][NSTATE];   // 4 KB state ring
    __shared__ uint8_t Farr[NSTATE * NSTATE];
    __shared__ uint8_t earr[NSTATE];
    __shared__ volatile int mp;                          // main progress
    __shared__ volatile int hpA;                         // odd-helper progress
    __shared__ volatile int hpB;                         // even-helper progress

    int* pred = (int*)&ring[0][0];                       // epilogue overlay

    if (tid == 0) { mp = 0; hpA = 0; hpB = 0; }

    int L = seqlen[blockIdx.x];
    L = min(max(L, 0), T_LEN);

    // transition column j, rows h16..h16+15 (all waves, identical layout)
    float tr[16];
#pragma unroll
    for (int k = 0; k < 16; ++k)
        tr[k] = trans[(h16 + k) * NSTATE + j];

    const float* lg = logits + (size_t)blockIdx.x * T_LEN * NSTATE;

    __syncthreads();     // mp/hp initialized

    int ft = 0;

    if (wid == 0) {
        // ========================= MAIN =========================
        __builtin_amdgcn_s_setprio(1);

        float ns = lg[j];                 // column-j value (dup lanes j, j+32)
        ring[0][j] = ns;                  // publish S_0
        __asm__ __volatile__("" ::: "memory");

        float4 q0, q1, q2, q3;
        {
            const float4* sv = (const float4*)(&ring[0][0]) + half * 4;
            q0 = sv[0]; q1 = sv[1]; q2 = sv[2]; q3 = sv[3];
        }

        auto mstep = [&](int t, float lgt) {
            float a0 = max3f(q0.x + tr[0],  q0.y + tr[1],  q0.z + tr[2]);
            float a1 = max3f(q0.w + tr[3],  q1.x + tr[4],  q1.y + tr[5]);
            float a2 = max3f(q1.z + tr[6],  q1.w + tr[7],  q2.x + tr[8]);
            float a3 = max3f(q2.y + tr[9],  q2.z + tr[10], q2.w + tr[11]);
            float a4 = max3f(q3.x + tr[12], q3.y + tr[13], q3.z + tr[14]);
            float b0 = max3f(a0, a1, a2);
            float b1 = max3f(a3, a4, q3.w + tr[15]);
            float hm = fmaxf(b0, b1);

            v2i sw = __builtin_amdgcn_permlane32_swap(__float_as_int(hm),
                                                      __float_as_int(hm), false, false);
            float gm = fmaxf(hm, fmaxf(__int_as_float(sw[0]), __int_as_float(sw[1])));

            ns = gm + lgt;                // reference add order

            // throttle (rarely binding; deadlock-free by construction)
            if ((t & 7) == 0) {
                while (min(hpA, hpB) < t - 20) __builtin_amdgcn_s_sleep(1);
            }

            float* row = &ring[t & (RING - 1)][0];
            row[j] = ns;                  // publish S_t (2-way dup write)
            __asm__ __volatile__("" ::: "memory");
            if (lane == 0) mp = t;        // single-lane progress post

            const float4* sv = (const float4*)row + half * 4;
            q0 = sv[0]; q1 = sv[1]; q2 = sv[2]; q3 = sv[3];   // next-step state
        };

        if (L >= 2) {
            float pre[8];
#pragma unroll
            for (int d = 0; d < 8; ++d)
                pre[d] = lg[min(1 + d, T_LEN - 1) * NSTATE + j];
            int t = 1;
            for (; t + 8 <= L; t += 8) {
#pragma unroll
                for (int u = 0; u < 8; ++u) {
                    mstep(t + u, pre[u]);
                    pre[u] = lg[min(t + 8 + u, T_LEN - 1) * NSTATE + j];
                }
            }
            for (int k2 = 0; t < L; ++t, ++k2) mstep(t, pre[k2]);
        }

        // last_tag = argmax(final state); lanes j and j+32 duplicate
        float m2 = ns;
#pragma unroll
        for (int d = 1; d < 64; d <<= 1) m2 = fmaxf(m2, __shfl_xor(m2, d));
        int ii = (ns == m2) ? j : 64;
#pragma unroll
        for (int d = 1; d < 64; d <<= 1) ii = min(ii, __shfl_xor(ii, d));
        ft = ii;
    } else {
        // ======================== HELPERS ========================
        volatile int* myhp = (wid == 1) ? &hpA : &hpB;

        auto hstep = [&](int t) {
            const float4* sv = (const float4*)(&ring[(t - 1) & (RING - 1)][0]) + half * 4;
            float4 q0 = sv[0], q1 = sv[1], q2 = sv[2], q3 = sv[3];

            float v[16];
            v[0]=q0.x+tr[0];  v[1]=q0.y+tr[1];  v[2]=q0.z+tr[2];  v[3]=q0.w+tr[3];
            v[4]=q1.x+tr[4];  v[5]=q1.y+tr[5];  v[6]=q1.z+tr[6];  v[7]=q1.w+tr[7];
            v[8]=q2.x+tr[8];  v[9]=q2.y+tr[9];  v[10]=q2.z+tr[10];v[11]=q2.w+tr[11];
            v[12]=q3.x+tr[12];v[13]=q3.y+tr[13];v[14]=q3.z+tr[14];v[15]=q3.w+tr[15];

            // gm recompute — fmax is assoc/comm: bit-identical to main's gm
            float a0 = max3f(v[0],  v[1],  v[2]);
            float a1 = max3f(v[3],  v[4],  v[5]);
            float a2 = max3f(v[6],  v[7],  v[8]);
            float a3 = max3f(v[9],  v[10], v[11]);
            float a4 = max3f(v[12], v[13], v[14]);
            float b0 = max3f(a0, a1, a2);
            float b1 = max3f(a3, a4, v[15]);
            float hm = fmaxf(b0, b1);
            v2i sw = __builtin_amdgcn_permlane32_swap(__float_as_int(hm),
                                                      __float_as_int(hm), false, false);
            float gm = fmaxf(hm, fmaxf(__int_as_float(sw[0]), __int_as_float(sw[1])));

            // exact first-occurrence argmax
            int ix[16];
#pragma unroll
            for (int k = 0; k < 16; ++k)
                ix[k] = (v[k] == gm) ? (h16 + k) : 64;
            int c0 = min3i(ix[0],  ix[1],  ix[2]);
            int c1 = min3i(ix[3],  ix[4],  ix[5]);
            int c2 = min3i(ix[6],  ix[7],  ix[8]);
            int c3 = min3i(ix[9],  ix[10], ix[11]);
            int c4 = min3i(ix[12], ix[13], ix[14]);
            int d0 = min3i(c0, c1, c2);
            int d1 = min3i(c3, c4, ix[15]);
            int ih = min(d0, d1);
            v2i swi = __builtin_amdgcn_permlane32_swap(ih, ih, false, false);
            int idx = min3i(ih, swi[0], swi[1]);

            bp[t * NSTATE + j] = (uint8_t)idx;   // 2-way dup same-value write
        };

        int t = (wid == 1) ? 1 : 2;              // my parity's first step
        // batches of 8 handled steps (t-range 16): one poll per batch
        for (; t + 14 <= L - 1; t += 16) {
            const int te = t + 14;               // last step of this batch
            while (mp < te) __builtin_amdgcn_s_sleep(1);
            __asm__ __volatile__("" ::: "memory");
#pragma unroll
            for (int u = 0; u < 8; ++u) hstep(t + 2 * u);
            if (lane == 0) *myhp = te;           // single-lane progress post
        }
        for (; t <= L - 1; t += 2) {             // tail: per-step poll
            while (mp < t) __builtin_amdgcn_s_sleep(1);
            __asm__ __volatile__("" ::: "memory");
            hstep(t);
        }
        if (lane == 0) *myhp = 1 << 20;          // full release
    }

    __syncthreads();   // bp complete; ring dead (pred overlays it)

    // ---- phase 1: chunk functions, all 32 start states (wave 0) ----
    if (wid == 0) {
        const int c = lane & 31;
        const int j0base = (lane >> 5) * 16;
        int tags[16];
#pragma unroll
        for (int k = 0; k < 16; ++k) tags[k] = j0base + k;
        const int thi = c * 32 + 31;
        for (int s = 0; s < 32; ++s) {
            int t = thi - s;
            bool valid = (t >= 1) && (t <= L - 1);
            int tc = min(max(t, 1), max(L - 1, 1));
            int base = tc * NSTATE;
#pragma unroll
            for (int k = 0; k < 16; ++k) {
                int nt = bp[base + tags[k]];
                tags[k] = valid ? nt : tags[k];
            }
        }
#pragma unroll
        for (int k = 0; k < 16; ++k)
            Farr[c * 32 + j0base + k] = (uint8_t)tags[k];
    }
    __syncthreads();

    // ---- phase 2: compose chunk entries ----
    if (tid == 0) {
        int e = ft;
        for (int c2 = 31; c2 >= 0; --c2) {
            earr[c2] = (uint8_t)e;
            e = Farr[c2 * 32 + e];
        }
    }
    __syncthreads();

    // ---- phase 3: re-walk chunks, emit pred (predication handles L<2) ----
    if (wid == 0 && lane < 32) {
        int tag = earr[lane];
        const int thi3 = lane * 32 + 31;
        for (int s = 0; s < 32; ++s) {
            int t = thi3 - s;
            pred[t] = (t < L) ? tag : 0;
            bool valid = (t >= 1) && (t <= L - 1);
            int tc = min(max(t, 1), max(L - 1, 1));
            int nt = bp[tc * NSTATE + tag];
            tag = valid ? nt : tag;
        }
    }
    __syncthreads();

    // ---------------- coalesced store (wave 0) ----------------
    if (wid == 0) {
        int4* out4 = reinterpret_cast<int4*>(out + (size_t)blockIdx.x * T_LEN);
        const int4* p4 = reinterpret_cast<const int4*>(pred);
#pragma unroll
        for (int r = 0; r < 4; ++r)
            out4[r * 64 + lane] = p4[r * 64 + lane];
    }
}

extern "C" void kernel_launch(void* const* d_in, const int* in_sizes, int n_in,
                              void* d_out, int out_size, void* d_ws, size_t ws_size,
                              hipStream_t stream) {
    const float* logits = (const float*)d_in[0];
    const float* trans  = (const float*)d_in[1];
    const int*   slen   = (const int*)d_in[2];
    int*         out    = (int*)d_out;
    const int B = in_sizes[2];   // 1024

    viterbi_kernel<<<dim3(B), dim3(192), 0, stream>>>(logits, trans, slen, out);
}